// Round 4
// baseline (236.933 us; speedup 1.0000x reference)
//
#include <hip/hip_runtime.h>

// InputDefenseLayer: clip(x, -3.5, 3.5) then EMA scan along T (axis 1):
//   s_0 = xc_0 ; s_t = 0.25*xc_t + 0.75*s_{t-1}
// x: (B=64, T=2048, C=256) float32, contiguous, C innermost.
//
// R5: ONE variable changed vs R4 -- regular stores instead of
// __builtin_nontemporal_store.
//  - R4 falsified the store-ack-coupling theory: loads-only consume chains,
//    8-deep prefetch, burst stores (provably newer than any waited-on load)
//    -> still 3.0 TB/s, same plateau as R1/R2.
//  - Remaining common feature of ALL plateau'd variants: nt stores. Theory:
//    nt bypasses L2/L3 -> fine-grained HBM writes interleaved with the read
//    stream -> bus-turnaround penalty on every direction switch. Cached
//    stores let the TCC batch dirty-line evictions into large writebacks.
//    Evidence: fillBufferAligned (regular stores) = 6.7 TB/s same session;
//    R3's scratch traffic (cached writes) pushed delivered BW to 3.37 TB/s
//    despite 30% junk bytes; 3.0/6.3 ~= 48% = classic turnaround band.
// Numerics identical to R1-R4: seed at t0-W, W=24 -> err 7*0.75^24 ~ 7e-3.

constexpr int B = 64;
constexpr int T = 2048;
constexpr int C = 256;
constexpr int L = 32;            // output chunk length along T
constexpr int W = 24;            // warm-up steps: 7*0.75^24 ~ 7e-3 < 7e-2
constexpr int NCHUNK = T / L;    // 64
constexpr int ROWF4 = C / 4;     // 64 float4 per t-row
constexpr int PF = 8;            // load prefetch depth

#define CLIP_LO -3.5f
#define CLIP_HI  3.5f
#define EMA_A 0.25f
#define EMA_B 0.75f

typedef float f4 __attribute__((ext_vector_type(4)));

__device__ __forceinline__ float clipf(float v) {
    return fminf(fmaxf(v, CLIP_LO), CLIP_HI);   // -> v_med3_f32
}

__device__ __forceinline__ f4 clip4(f4 v) {
    f4 r;
    r.x = clipf(v.x);
    r.y = clipf(v.y);
    r.z = clipf(v.z);
    r.w = clipf(v.w);
    return r;
}

__device__ __forceinline__ f4 ema4(f4 s, f4 v) {
    f4 r;
    r.x = fmaf(EMA_A, v.x, EMA_B * s.x);
    r.y = fmaf(EMA_A, v.y, EMA_B * s.y);
    r.z = fmaf(EMA_A, v.z, EMA_B * s.z);
    r.w = fmaf(EMA_A, v.w, EMA_B * s.w);
    return r;
}

// Consume row r from prefetch register p##j; re-issue load for row r+PF.
// No store (warm-up). All guards fold at compile time (r, N constants).
#define STEP(j, r)                                                   \
    {                                                                \
        f4 v = clip4(p##j);                                          \
        s = ((r) == 0) ? v : ema4(s, v);                             \
        if ((r) + PF < N) p##j = xp[((r) + PF) * ROWF4];             \
    }

// Same, but also latch the state into output register oo (named, static).
#define OSTEP(j, r, oo)                                              \
    {                                                                \
        f4 v = clip4(p##j);                                          \
        s = ((r) == 0) ? v : ema4(s, v);                             \
        oo = s;                                                      \
        if ((r) + PF < N) p##j = xp[((r) + PF) * ROWF4];             \
    }

// 8 warm-up rows starting at compile-time row r0.
#define G8W(r0)                                                      \
    STEP(0, (r0) + 0) STEP(1, (r0) + 1) STEP(2, (r0) + 2)            \
    STEP(3, (r0) + 3) STEP(4, (r0) + 4) STEP(5, (r0) + 5)            \
    STEP(6, (r0) + 6) STEP(7, (r0) + 7)

// 8 output rows starting at r0, latched into o0..o7 (loads-only vmcnt
// stream in this region), then a pinned back-to-back store burst.
// Stores are REGULAR (cache-allocating): the TCC batches dirty-line
// writebacks -> large HBM write bursts instead of fine-grained nt writes
// interleaved with the read stream.
#define G8S(r0)                                                      \
    OSTEP(0, (r0) + 0, o0) OSTEP(1, (r0) + 1, o1)                    \
    OSTEP(2, (r0) + 2, o2) OSTEP(3, (r0) + 3, o3)                    \
    OSTEP(4, (r0) + 4, o4) OSTEP(5, (r0) + 5, o5)                    \
    OSTEP(6, (r0) + 6, o6) OSTEP(7, (r0) + 7, o7)                    \
    __builtin_amdgcn_sched_barrier(0);                               \
    op[((r0) + 0) * ROWF4] = o0;                                     \
    op[((r0) + 1) * ROWF4] = o1;                                     \
    op[((r0) + 2) * ROWF4] = o2;                                     \
    op[((r0) + 3) * ROWF4] = o3;                                     \
    op[((r0) + 4) * ROWF4] = o4;                                     \
    op[((r0) + 5) * ROWF4] = o5;                                     \
    op[((r0) + 6) * ROWF4] = o6;                                     \
    op[((r0) + 7) * ROWF4] = o7;                                     \
    __builtin_amdgcn_sched_barrier(0);

// Process rows [0, N): row 0 seeds the EMA state, rows >= SKIP are stored.
template <int N, int SKIP>
__device__ __forceinline__ void run_rows(const f4* __restrict__ xp,
                                         f4* __restrict__ op) {
    f4 p0 = xp[0 * ROWF4];
    f4 p1 = xp[1 * ROWF4];
    f4 p2 = xp[2 * ROWF4];
    f4 p3 = xp[3 * ROWF4];
    f4 p4 = xp[4 * ROWF4];
    f4 p5 = xp[5 * ROWF4];
    f4 p6 = xp[6 * ROWF4];
    f4 p7 = xp[7 * ROWF4];
    f4 s = {};
    f4 o0, o1, o2, o3, o4, o5, o6, o7;

    if constexpr (SKIP == 0) {
        static_assert(N == L, "k==0 path is 32 rows");
        G8S(0)
        G8S(8)
        G8S(16)
        G8S(24)
    } else {
        static_assert(SKIP == W && N == W + L, "warm-up path is 24+32 rows");
        G8W(0)
        G8W(8)
        G8W(16)
        G8S(24)
        G8S(32)
        G8S(40)
        G8S(48)
    }
}

__global__ __launch_bounds__(256, 2) void ema_kernel(
    const float* __restrict__ x, float* __restrict__ out)
{
    // 4 chunk-jobs per 256-thread block; 64 float4-lanes (1 wave) each.
    const int job  = blockIdx.x * 4 + (threadIdx.x >> 6);
    const int lane = threadIdx.x & 63;
    const int b    = job >> 6;            // / NCHUNK
    const int k    = job & (NCHUNK - 1);  // % NCHUNK
    const int t0   = k * L;
    const int tb   = (k == 0) ? 0 : (t0 - W);

    const f4* __restrict__ xp = (const f4*)x + ((size_t)b * T + tb) * ROWF4 + lane;
    f4* __restrict__ op       = (f4*)out     + ((size_t)b * T + tb) * ROWF4 + lane;

    if (k == 0) {
        run_rows<L, 0>(xp, op);           // exact from t=0, store all 32 rows
    } else {
        run_rows<W + L, W>(xp, op);       // 24 warm-up rows, store last 32
    }
}

extern "C" void kernel_launch(void* const* d_in, const int* in_sizes, int n_in,
                              void* d_out, int out_size, void* d_ws, size_t ws_size,
                              hipStream_t stream) {
    const float* x = (const float*)d_in[0];
    float* out = (float*)d_out;
    const int n_jobs = B * NCHUNK;                 // 4096
    ema_kernel<<<dim3(n_jobs / 4), dim3(256), 0, stream>>>(x, out);
}

// Round 5
// 232.229 us; speedup vs baseline: 1.0203x; 1.0203x over previous
//
#include <hip/hip_runtime.h>

// InputDefenseLayer: clip(x, -3.5, 3.5) then EMA scan along T (axis 1):
//   s_0 = xc_0 ; s_t = 0.25*xc_t + 0.75*s_{t-1}
// x: (B=64, T=2048, C=256) float32, contiguous, C innermost.
//
// R6: ONE variable changed vs R5 -- the kernel is made fully NON-ALLOCATING
// in L2/L3: nt LOADS (__builtin_nontemporal_load) + nt stores.
//  - Falsified so far (all flat at 3.0 TB/s): bytes-in-flight (4->28 MB),
//    store-ack vmcnt coupling (burst-decoupled), nt-vs-cached stores,
//    instantaneous footprint density (5%->25%).
//  - Surviving theory: the harness's reset() runs a 512 MiB cached
//    fillBufferAligned between iterations, leaving the 256 MiB L3 entirely
//    DIRTY. Our kernel touches 256 MiB of address space; every read-miss
//    allocate and write-allocate must first evict a dirty fill line to HBM.
//    Real bus traffic during our window ~= 113R + 128W + ~256 MB deferred
//    fill writebacks ~= 500 MB / 83 us ~= 6 TB/s -- already at the copy
//    ceiling, half spent on another kernel's laundry. Every prior round
//    allocated on the READ side identically -> explains all invariances.
//  - Fix under test: never allocate -> never evict fill dirt in-window.
// Numerics identical to R1-R5: seed at t0-W, W=24 -> err 7*0.75^24 ~ 7e-3.

constexpr int B = 64;
constexpr int T = 2048;
constexpr int C = 256;
constexpr int L = 32;            // output chunk length along T
constexpr int W = 24;            // warm-up steps: 7*0.75^24 ~ 7e-3 < 7e-2
constexpr int NCHUNK = T / L;    // 64
constexpr int ROWF4 = C / 4;     // 64 float4 per t-row
constexpr int PF = 8;            // load prefetch depth

#define CLIP_LO -3.5f
#define CLIP_HI  3.5f
#define EMA_A 0.25f
#define EMA_B 0.75f

typedef float f4 __attribute__((ext_vector_type(4)));

__device__ __forceinline__ float clipf(float v) {
    return fminf(fmaxf(v, CLIP_LO), CLIP_HI);   // -> v_med3_f32
}

__device__ __forceinline__ f4 clip4(f4 v) {
    f4 r;
    r.x = clipf(v.x);
    r.y = clipf(v.y);
    r.z = clipf(v.z);
    r.w = clipf(v.w);
    return r;
}

__device__ __forceinline__ f4 ema4(f4 s, f4 v) {
    f4 r;
    r.x = fmaf(EMA_A, v.x, EMA_B * s.x);
    r.y = fmaf(EMA_A, v.y, EMA_B * s.y);
    r.z = fmaf(EMA_A, v.z, EMA_B * s.z);
    r.w = fmaf(EMA_A, v.w, EMA_B * s.w);
    return r;
}

// Non-temporal (non-allocating) 16-B load/store.
#define NTLOAD(p)     __builtin_nontemporal_load(p)
#define NTSTORE(v, p) __builtin_nontemporal_store((v), (p))

// Consume row r from prefetch register p##j; re-issue load for row r+PF.
// No store (warm-up). All guards fold at compile time (r, N constants).
#define STEP(j, r)                                                   \
    {                                                                \
        f4 v = clip4(p##j);                                          \
        s = ((r) == 0) ? v : ema4(s, v);                             \
        if ((r) + PF < N) p##j = NTLOAD(&xp[((r) + PF) * ROWF4]);    \
    }

// Same, but also latch the state into output register oo (named, static).
#define OSTEP(j, r, oo)                                              \
    {                                                                \
        f4 v = clip4(p##j);                                          \
        s = ((r) == 0) ? v : ema4(s, v);                             \
        oo = s;                                                      \
        if ((r) + PF < N) p##j = NTLOAD(&xp[((r) + PF) * ROWF4]);    \
    }

// 8 warm-up rows starting at compile-time row r0.
#define G8W(r0)                                                      \
    STEP(0, (r0) + 0) STEP(1, (r0) + 1) STEP(2, (r0) + 2)            \
    STEP(3, (r0) + 3) STEP(4, (r0) + 4) STEP(5, (r0) + 5)            \
    STEP(6, (r0) + 6) STEP(7, (r0) + 7)

// 8 output rows starting at r0, latched into o0..o7 (loads-only vmcnt
// stream in this region), then a pinned back-to-back nt store burst.
#define G8S(r0)                                                      \
    OSTEP(0, (r0) + 0, o0) OSTEP(1, (r0) + 1, o1)                    \
    OSTEP(2, (r0) + 2, o2) OSTEP(3, (r0) + 3, o3)                    \
    OSTEP(4, (r0) + 4, o4) OSTEP(5, (r0) + 5, o5)                    \
    OSTEP(6, (r0) + 6, o6) OSTEP(7, (r0) + 7, o7)                    \
    __builtin_amdgcn_sched_barrier(0);                               \
    NTSTORE(o0, op + ((r0) + 0) * ROWF4);                            \
    NTSTORE(o1, op + ((r0) + 1) * ROWF4);                            \
    NTSTORE(o2, op + ((r0) + 2) * ROWF4);                            \
    NTSTORE(o3, op + ((r0) + 3) * ROWF4);                            \
    NTSTORE(o4, op + ((r0) + 4) * ROWF4);                            \
    NTSTORE(o5, op + ((r0) + 5) * ROWF4);                            \
    NTSTORE(o6, op + ((r0) + 6) * ROWF4);                            \
    NTSTORE(o7, op + ((r0) + 7) * ROWF4);                            \
    __builtin_amdgcn_sched_barrier(0);

// Process rows [0, N): row 0 seeds the EMA state, rows >= SKIP are stored.
template <int N, int SKIP>
__device__ __forceinline__ void run_rows(const f4* __restrict__ xp,
                                         f4* __restrict__ op) {
    f4 p0 = NTLOAD(&xp[0 * ROWF4]);
    f4 p1 = NTLOAD(&xp[1 * ROWF4]);
    f4 p2 = NTLOAD(&xp[2 * ROWF4]);
    f4 p3 = NTLOAD(&xp[3 * ROWF4]);
    f4 p4 = NTLOAD(&xp[4 * ROWF4]);
    f4 p5 = NTLOAD(&xp[5 * ROWF4]);
    f4 p6 = NTLOAD(&xp[6 * ROWF4]);
    f4 p7 = NTLOAD(&xp[7 * ROWF4]);
    f4 s = {};
    f4 o0, o1, o2, o3, o4, o5, o6, o7;

    if constexpr (SKIP == 0) {
        static_assert(N == L, "k==0 path is 32 rows");
        G8S(0)
        G8S(8)
        G8S(16)
        G8S(24)
    } else {
        static_assert(SKIP == W && N == W + L, "warm-up path is 24+32 rows");
        G8W(0)
        G8W(8)
        G8W(16)
        G8S(24)
        G8S(32)
        G8S(40)
        G8S(48)
    }
}

__global__ __launch_bounds__(256, 2) void ema_kernel(
    const float* __restrict__ x, float* __restrict__ out)
{
    // 4 chunk-jobs per 256-thread block; 64 float4-lanes (1 wave) each.
    const int job  = blockIdx.x * 4 + (threadIdx.x >> 6);
    const int lane = threadIdx.x & 63;
    const int b    = job >> 6;            // / NCHUNK
    const int k    = job & (NCHUNK - 1);  // % NCHUNK
    const int t0   = k * L;
    const int tb   = (k == 0) ? 0 : (t0 - W);

    const f4* __restrict__ xp = (const f4*)x + ((size_t)b * T + tb) * ROWF4 + lane;
    f4* __restrict__ op       = (f4*)out     + ((size_t)b * T + tb) * ROWF4 + lane;

    if (k == 0) {
        run_rows<L, 0>(xp, op);           // exact from t=0, store all 32 rows
    } else {
        run_rows<W + L, W>(xp, op);       // 24 warm-up rows, store last 32
    }
}

extern "C" void kernel_launch(void* const* d_in, const int* in_sizes, int n_in,
                              void* d_out, int out_size, void* d_ws, size_t ws_size,
                              hipStream_t stream) {
    const float* x = (const float*)d_in[0];
    float* out = (float*)d_out;
    const int n_jobs = B * NCHUNK;                 // 4096
    ema_kernel<<<dim3(n_jobs / 4), dim3(256), 0, stream>>>(x, out);
}

// Round 6
// 228.382 us; speedup vs baseline: 1.0374x; 1.0168x over previous
//
#include <hip/hip_runtime.h>

// InputDefenseLayer: clip(x, -3.5, 3.5) then EMA scan along T (axis 1):
//   s_0 = xc_0 ; s_t = 0.25*xc_t + 0.75*s_{t-1}
// x: (B=64, T=2048, C=256) float32, contiguous, C innermost.
//
// R7: ONE structural change vs R6 -- chunk length L 32 -> 64.
//  - R6 (fully non-allocating: nt loads + nt stores) broke the 3.0 TB/s
//    plateau: ema dropped below the 78.6 us fill dispatches (~75 us est).
//    Confirms the L3-dirty-eviction theory: not allocating means not
//    evicting the reset-fill's dirty lines inside our timing window.
//  - But nt loads also un-absorbed the warm-up re-reads: read
//    amplification (32+63*56)/2048 = 1.74x -> ~222 MB FETCH, ~4.5 TB/s
//    delivered. Warm-up cost is per-chunk, so L=64 cuts amplification to
//    (64+31*88)/2048 = 1.36x (~175 MB FETCH, total 303 vs 350 MB).
//  - Waves 4096 -> 2048 (2/SIMD). In-flight/SIMD = 2 waves x 8 KiB = 16 KiB
//    -> 16 MB device-wide, above the ~8 MB Little's-law need at ~1.2 us
//    loaded latency. (L=128 would drop to 1 wave/SIMD -- deferred.)
// Numerics: same seed structure, W=24 -> err 7*0.75^24 ~ 7e-3 < 7e-2.

constexpr int B = 64;
constexpr int T = 2048;
constexpr int C = 256;
constexpr int L = 64;            // output chunk length along T (R7: was 32)
constexpr int W = 24;            // warm-up steps: 7*0.75^24 ~ 7e-3 < 7e-2
constexpr int NCHUNK = T / L;    // 32
constexpr int ROWF4 = C / 4;     // 64 float4 per t-row
constexpr int PF = 8;            // load prefetch depth

#define CLIP_LO -3.5f
#define CLIP_HI  3.5f
#define EMA_A 0.25f
#define EMA_B 0.75f

typedef float f4 __attribute__((ext_vector_type(4)));

__device__ __forceinline__ float clipf(float v) {
    return fminf(fmaxf(v, CLIP_LO), CLIP_HI);   // -> v_med3_f32
}

__device__ __forceinline__ f4 clip4(f4 v) {
    f4 r;
    r.x = clipf(v.x);
    r.y = clipf(v.y);
    r.z = clipf(v.z);
    r.w = clipf(v.w);
    return r;
}

__device__ __forceinline__ f4 ema4(f4 s, f4 v) {
    f4 r;
    r.x = fmaf(EMA_A, v.x, EMA_B * s.x);
    r.y = fmaf(EMA_A, v.y, EMA_B * s.y);
    r.z = fmaf(EMA_A, v.z, EMA_B * s.z);
    r.w = fmaf(EMA_A, v.w, EMA_B * s.w);
    return r;
}

// Non-temporal (non-allocating) 16-B load/store.
#define NTLOAD(p)     __builtin_nontemporal_load(p)
#define NTSTORE(v, p) __builtin_nontemporal_store((v), (p))

// Consume row r from prefetch register p##j; re-issue load for row r+PF.
// No store (warm-up). All guards fold at compile time (r, N constants).
#define STEP(j, r)                                                   \
    {                                                                \
        f4 v = clip4(p##j);                                          \
        s = ((r) == 0) ? v : ema4(s, v);                             \
        if ((r) + PF < N) p##j = NTLOAD(&xp[((r) + PF) * ROWF4]);    \
    }

// Same, but also latch the state into output register oo (named, static).
#define OSTEP(j, r, oo)                                              \
    {                                                                \
        f4 v = clip4(p##j);                                          \
        s = ((r) == 0) ? v : ema4(s, v);                             \
        oo = s;                                                      \
        if ((r) + PF < N) p##j = NTLOAD(&xp[((r) + PF) * ROWF4]);    \
    }

// 8 warm-up rows starting at compile-time row r0.
#define G8W(r0)                                                      \
    STEP(0, (r0) + 0) STEP(1, (r0) + 1) STEP(2, (r0) + 2)            \
    STEP(3, (r0) + 3) STEP(4, (r0) + 4) STEP(5, (r0) + 5)            \
    STEP(6, (r0) + 6) STEP(7, (r0) + 7)

// 8 output rows starting at r0, latched into o0..o7 (loads-only vmcnt
// stream in this region), then a pinned back-to-back nt store burst.
#define G8S(r0)                                                      \
    OSTEP(0, (r0) + 0, o0) OSTEP(1, (r0) + 1, o1)                    \
    OSTEP(2, (r0) + 2, o2) OSTEP(3, (r0) + 3, o3)                    \
    OSTEP(4, (r0) + 4, o4) OSTEP(5, (r0) + 5, o5)                    \
    OSTEP(6, (r0) + 6, o6) OSTEP(7, (r0) + 7, o7)                    \
    __builtin_amdgcn_sched_barrier(0);                               \
    NTSTORE(o0, op + ((r0) + 0) * ROWF4);                            \
    NTSTORE(o1, op + ((r0) + 1) * ROWF4);                            \
    NTSTORE(o2, op + ((r0) + 2) * ROWF4);                            \
    NTSTORE(o3, op + ((r0) + 3) * ROWF4);                            \
    NTSTORE(o4, op + ((r0) + 4) * ROWF4);                            \
    NTSTORE(o5, op + ((r0) + 5) * ROWF4);                            \
    NTSTORE(o6, op + ((r0) + 6) * ROWF4);                            \
    NTSTORE(o7, op + ((r0) + 7) * ROWF4);                            \
    __builtin_amdgcn_sched_barrier(0);

// Process rows [0, N): row 0 seeds the EMA state, rows >= SKIP are stored.
template <int N, int SKIP>
__device__ __forceinline__ void run_rows(const f4* __restrict__ xp,
                                         f4* __restrict__ op) {
    f4 p0 = NTLOAD(&xp[0 * ROWF4]);
    f4 p1 = NTLOAD(&xp[1 * ROWF4]);
    f4 p2 = NTLOAD(&xp[2 * ROWF4]);
    f4 p3 = NTLOAD(&xp[3 * ROWF4]);
    f4 p4 = NTLOAD(&xp[4 * ROWF4]);
    f4 p5 = NTLOAD(&xp[5 * ROWF4]);
    f4 p6 = NTLOAD(&xp[6 * ROWF4]);
    f4 p7 = NTLOAD(&xp[7 * ROWF4]);
    f4 s = {};
    f4 o0, o1, o2, o3, o4, o5, o6, o7;

    if constexpr (SKIP == 0) {
        static_assert(N == L, "k==0 path is 64 rows");
        G8S(0)
        G8S(8)
        G8S(16)
        G8S(24)
        G8S(32)
        G8S(40)
        G8S(48)
        G8S(56)
    } else {
        static_assert(SKIP == W && N == W + L, "warm-up path is 24+64 rows");
        G8W(0)
        G8W(8)
        G8W(16)
        G8S(24)
        G8S(32)
        G8S(40)
        G8S(48)
        G8S(56)
        G8S(64)
        G8S(72)
        G8S(80)
    }
}

__global__ __launch_bounds__(256, 2) void ema_kernel(
    const float* __restrict__ x, float* __restrict__ out)
{
    // 4 chunk-jobs per 256-thread block; 64 float4-lanes (1 wave) each.
    const int job  = blockIdx.x * 4 + (threadIdx.x >> 6);
    const int lane = threadIdx.x & 63;
    const int b    = job >> 5;            // / NCHUNK (32)
    const int k    = job & (NCHUNK - 1);  // % NCHUNK
    const int t0   = k * L;
    const int tb   = (k == 0) ? 0 : (t0 - W);

    const f4* __restrict__ xp = (const f4*)x + ((size_t)b * T + tb) * ROWF4 + lane;
    f4* __restrict__ op       = (f4*)out     + ((size_t)b * T + tb) * ROWF4 + lane;

    if (k == 0) {
        run_rows<L, 0>(xp, op);           // exact from t=0, store all 64 rows
    } else {
        run_rows<W + L, W>(xp, op);       // 24 warm-up rows, store last 64
    }
}

extern "C" void kernel_launch(void* const* d_in, const int* in_sizes, int n_in,
                              void* d_out, int out_size, void* d_ws, size_t ws_size,
                              hipStream_t stream) {
    const float* x = (const float*)d_in[0];
    float* out = (float*)d_out;
    const int n_jobs = B * NCHUNK;                 // 2048
    ema_kernel<<<dim3(n_jobs / 4), dim3(256), 0, stream>>>(x, out);
}

// Round 7
// 226.432 us; speedup vs baseline: 1.0464x; 1.0086x over previous
//
#include <hip/hip_runtime.h>

// InputDefenseLayer: clip(x, -3.5, 3.5) then EMA scan along T (axis 1):
//   s_0 = xc_0 ; s_t = 0.25*xc_t + 0.75*s_{t-1}
// x: (B=64, T=2048, C=256) float32, contiguous, C innermost.
//
// R8: decouple traffic from wave count. L stays 64 (amplification 1.36x,
// 303 MB total), but each chunk is now handled by TWO waves of float2
// lanes (C split in halves: 64 lanes x 8 B = 512 B per row per wave).
//  - Evidence: R6 (4096 waves, 350 MB) delivered ~4.67 TB/s; R7 (2048
//    waves, 303 MB) only ~4.27 TB/s -- rate correlates with wave count in
//    the non-allocating (nt) regime. C-split restores 4096 waves (4/SIMD)
//    at L=64's traffic. Outstanding bytes unchanged (requests halve in
//    size, double in count).
//  - nt loads AND nt stores kept: the only regime that broke the 3.0 TB/s
//    L3-dirty-eviction plateau (R6).
// Numerics: same W=24 seed, same per-element fmaf order -> absmax
// unchanged (0.0078125, 10x under threshold).

constexpr int B = 64;
constexpr int T = 2048;
constexpr int C = 256;
constexpr int L = 64;            // output chunk length along T
constexpr int W = 24;            // warm-up steps: 7*0.75^24 ~ 7e-3 < 7e-2
constexpr int NCHUNK = T / L;    // 32
constexpr int ROWF2 = C / 2;     // 128 float2 per t-row
constexpr int PF = 8;            // load prefetch depth

#define CLIP_LO -3.5f
#define CLIP_HI  3.5f
#define EMA_A 0.25f
#define EMA_B 0.75f

typedef float f2 __attribute__((ext_vector_type(2)));

__device__ __forceinline__ float clipf(float v) {
    return fminf(fmaxf(v, CLIP_LO), CLIP_HI);   // -> v_med3_f32
}

__device__ __forceinline__ f2 clip2(f2 v) {
    f2 r;
    r.x = clipf(v.x);
    r.y = clipf(v.y);
    return r;
}

__device__ __forceinline__ f2 ema2(f2 s, f2 v) {
    f2 r;
    r.x = fmaf(EMA_A, v.x, EMA_B * s.x);
    r.y = fmaf(EMA_A, v.y, EMA_B * s.y);
    return r;
}

// Non-temporal (non-allocating) 8-B load/store.
#define NTLOAD(p)     __builtin_nontemporal_load(p)
#define NTSTORE(v, p) __builtin_nontemporal_store((v), (p))

// Consume row r from prefetch register p##j; re-issue load for row r+PF.
// No store (warm-up). All guards fold at compile time (r, N constants).
#define STEP(j, r)                                                   \
    {                                                                \
        f2 v = clip2(p##j);                                          \
        s = ((r) == 0) ? v : ema2(s, v);                             \
        if ((r) + PF < N) p##j = NTLOAD(&xp[((r) + PF) * ROWF2]);    \
    }

// Same, but also latch the state into output register oo (named, static).
#define OSTEP(j, r, oo)                                              \
    {                                                                \
        f2 v = clip2(p##j);                                          \
        s = ((r) == 0) ? v : ema2(s, v);                             \
        oo = s;                                                      \
        if ((r) + PF < N) p##j = NTLOAD(&xp[((r) + PF) * ROWF2]);    \
    }

// 8 warm-up rows starting at compile-time row r0.
#define G8W(r0)                                                      \
    STEP(0, (r0) + 0) STEP(1, (r0) + 1) STEP(2, (r0) + 2)            \
    STEP(3, (r0) + 3) STEP(4, (r0) + 4) STEP(5, (r0) + 5)            \
    STEP(6, (r0) + 6) STEP(7, (r0) + 7)

// 8 output rows starting at r0, latched into o0..o7 (loads-only vmcnt
// stream in this region), then a pinned back-to-back nt store burst.
#define G8S(r0)                                                      \
    OSTEP(0, (r0) + 0, o0) OSTEP(1, (r0) + 1, o1)                    \
    OSTEP(2, (r0) + 2, o2) OSTEP(3, (r0) + 3, o3)                    \
    OSTEP(4, (r0) + 4, o4) OSTEP(5, (r0) + 5, o5)                    \
    OSTEP(6, (r0) + 6, o6) OSTEP(7, (r0) + 7, o7)                    \
    __builtin_amdgcn_sched_barrier(0);                               \
    NTSTORE(o0, op + ((r0) + 0) * ROWF2);                            \
    NTSTORE(o1, op + ((r0) + 1) * ROWF2);                            \
    NTSTORE(o2, op + ((r0) + 2) * ROWF2);                            \
    NTSTORE(o3, op + ((r0) + 3) * ROWF2);                            \
    NTSTORE(o4, op + ((r0) + 4) * ROWF2);                            \
    NTSTORE(o5, op + ((r0) + 5) * ROWF2);                            \
    NTSTORE(o6, op + ((r0) + 6) * ROWF2);                            \
    NTSTORE(o7, op + ((r0) + 7) * ROWF2);                            \
    __builtin_amdgcn_sched_barrier(0);

// Process rows [0, N): row 0 seeds the EMA state, rows >= SKIP are stored.
template <int N, int SKIP>
__device__ __forceinline__ void run_rows(const f2* __restrict__ xp,
                                         f2* __restrict__ op) {
    f2 p0 = NTLOAD(&xp[0 * ROWF2]);
    f2 p1 = NTLOAD(&xp[1 * ROWF2]);
    f2 p2 = NTLOAD(&xp[2 * ROWF2]);
    f2 p3 = NTLOAD(&xp[3 * ROWF2]);
    f2 p4 = NTLOAD(&xp[4 * ROWF2]);
    f2 p5 = NTLOAD(&xp[5 * ROWF2]);
    f2 p6 = NTLOAD(&xp[6 * ROWF2]);
    f2 p7 = NTLOAD(&xp[7 * ROWF2]);
    f2 s = {};
    f2 o0, o1, o2, o3, o4, o5, o6, o7;

    if constexpr (SKIP == 0) {
        static_assert(N == L, "k==0 path is 64 rows");
        G8S(0)
        G8S(8)
        G8S(16)
        G8S(24)
        G8S(32)
        G8S(40)
        G8S(48)
        G8S(56)
    } else {
        static_assert(SKIP == W && N == W + L, "warm-up path is 24+64 rows");
        G8W(0)
        G8W(8)
        G8W(16)
        G8S(24)
        G8S(32)
        G8S(40)
        G8S(48)
        G8S(56)
        G8S(64)
        G8S(72)
        G8S(80)
    }
}

__global__ __launch_bounds__(256, 2) void ema_kernel(
    const float* __restrict__ x, float* __restrict__ out)
{
    // 4 jobs per 256-thread block; each job = one wave = half a chunk's C.
    const int job  = blockIdx.x * 4 + (threadIdx.x >> 6);
    const int lane = threadIdx.x & 63;
    const int half = job & 1;             // which C-half this wave owns
    const int chnk = job >> 1;            // chunk id: 0 .. B*NCHUNK-1
    const int b    = chnk >> 5;           // / NCHUNK (32)
    const int k    = chnk & (NCHUNK - 1); // % NCHUNK
    const int t0   = k * L;
    const int tb   = (k == 0) ? 0 : (t0 - W);

    const f2* __restrict__ xp =
        (const f2*)x + ((size_t)b * T + tb) * ROWF2 + half * 64 + lane;
    f2* __restrict__ op =
        (f2*)out     + ((size_t)b * T + tb) * ROWF2 + half * 64 + lane;

    if (k == 0) {
        run_rows<L, 0>(xp, op);           // exact from t=0, store all 64 rows
    } else {
        run_rows<W + L, W>(xp, op);       // 24 warm-up rows, store last 64
    }
}

extern "C" void kernel_launch(void* const* d_in, const int* in_sizes, int n_in,
                              void* d_out, int out_size, void* d_ws, size_t ws_size,
                              hipStream_t stream) {
    const float* x = (const float*)d_in[0];
    float* out = (float*)d_out;
    const int n_jobs = B * NCHUNK * 2;             // 4096
    ema_kernel<<<dim3(n_jobs / 4), dim3(256), 0, stream>>>(x, out);
}